// Round 7
// baseline (86.747 us; speedup 1.0000x reference)
//
#include <hip/hip_runtime.h>
#include <stdint.h>

typedef __bf16 bf16x8 __attribute__((ext_vector_type(8)));
typedef float f32x4 __attribute__((ext_vector_type(4)));

#define EPS 1e-5f

// ---- workspace layout (bytes) ----
#define OFF_V     0                       // V f32 128x2048 = 1 MB
#define OFF_SQ    1048576                 // 12 x 64 f32 qkv BN-stat partials
#define OFF_SDOT  (OFF_SQ + 4096)         // 64nt x 64b x 8 f32 dot partials = 128 KB
#define OFF_SO    (OFF_SDOT + 131072)     // 64 x 4 f32 out BN partials
#define OFF_PROJ  (OFF_SO + 4096)         // 128x1024 f32 = 512 KB

__device__ __forceinline__ float wave_red(float v) {
#pragma unroll
  for (int o = 32; o > 0; o >>= 1) v += __shfl_down(v, o);
  return v;
}

#define GLDS16(g, l)                                             \
  __builtin_amdgcn_global_load_lds(                              \
      (const __attribute__((address_space(1))) void*)(g),        \
      (__attribute__((address_space(3))) void*)(l), 16, 0, 0)

// read 8 consecutive-K f32 from LDS (chunk index p0, pre-swizzled even) and
// split into hi/lo bf16x8
static __device__ __forceinline__ void frag_split(const float* base, int p0,
                                                  bf16x8& hi, bf16x8& lo) {
  float4 v0 = *(const float4*)(base + p0 * 4);
  float4 v1 = *(const float4*)(base + p0 * 4 + 4);
  float a[8] = {v0.x, v0.y, v0.z, v0.w, v1.x, v1.y, v1.z, v1.w};
#pragma unroll
  for (int i = 0; i < 8; ++i) {
    __bf16 h = (__bf16)a[i];
    hi[i] = h;
    lo[i] = (__bf16)(a[i] - (float)h);
  }
}
static __device__ __forceinline__ bf16x8 frag_cvt(const float* base, int p0) {
  float4 v0 = *(const float4*)(base + p0 * 4);
  float4 v1 = *(const float4*)(base + p0 * 4 + 4);
  bf16x8 r;
  r[0] = (__bf16)v0.x; r[1] = (__bf16)v0.y; r[2] = (__bf16)v0.z; r[3] = (__bf16)v0.w;
  r[4] = (__bf16)v1.x; r[5] = (__bf16)v1.y; r[6] = (__bf16)v1.z; r[7] = (__bf16)v1.w;
  return r;
}

// ============== K1: colocated q/k/v GEMM + raw dot/stat partials ==============
// grid 64 (n-tiles of 32 cols), 512 threads (8 waves, 16 rows each).
// A(x) 2-buf 1-ahead (L2-hot), B(W q|k|v, 96x64) 3-buf 2-ahead.
__global__ __launch_bounds__(512) void qkv_gemm(const float* __restrict__ x,
                                                const float* __restrict__ Wq,
                                                const float* __restrict__ Wk,
                                                const float* __restrict__ Wv,
                                                float* __restrict__ V,
                                                float* __restrict__ sq,
                                                float* __restrict__ sdot) {
  __shared__ alignas(16) float Af[2][128 * 64];   // 64 KB
  __shared__ alignas(16) float Bf[3][96 * 64];    // 72 KB
  __shared__ float red[96];

  const int nt = blockIdx.x;
  const int tid = threadIdx.x, w = tid >> 6, lane = tid & 63;
  const int rsel = lane >> 4, ch = lane & 15, l15 = lane & 15;

#define STAGE_A(c, tt) do {                                                   \
    _Pragma("unroll")                                                         \
    for (int j = 0; j < 4; ++j) {                                             \
      int rl = w * 16 + j * 4 + rsel;                                         \
      GLDS16(x + rl * 1024 + (tt) * 64 + ((ch ^ ((rl & 7) << 1)) << 2),       \
             &Af[c][(w * 16 + j * 4) * 64]);                                  \
    }                                                                         \
  } while (0)

#define STAGE_B(c, tt) do {                                                   \
    _Pragma("unroll")                                                         \
    for (int j = 0; j < 3; ++j) {                                             \
      int br = w * 12 + j * 4;                                                \
      int rl = br + rsel;                                                     \
      const float* wb = (br < 32) ? Wq : ((br < 64) ? Wk : Wv);               \
      GLDS16(wb + (nt * 32 + (rl & 31)) * 1024 + (tt) * 64 +                  \
                 ((ch ^ ((rl & 7) << 1)) << 2),                               \
             &Bf[c][br * 64]);                                                \
    }                                                                         \
  } while (0)

  f32x4 aq[2], ak[2], av[2];
#pragma unroll
  for (int n = 0; n < 2; ++n) {
    aq[n] = (f32x4){0.f, 0.f, 0.f, 0.f};
    ak[n] = (f32x4){0.f, 0.f, 0.f, 0.f};
    av[n] = (f32x4){0.f, 0.f, 0.f, 0.f};
  }

  // prologue: A(0), B(0), B(1); keep B(1) in flight
  STAGE_A(0, 0);
  STAGE_B(0, 0);
  STAGE_B(1, 1);
  asm volatile("s_waitcnt vmcnt(3) lgkmcnt(0)" ::: "memory");
  __builtin_amdgcn_sched_barrier(0);
  __builtin_amdgcn_s_barrier();
  __builtin_amdgcn_sched_barrier(0);

  const int ra = w * 16 + l15;
#pragma unroll
  for (int t = 0; t < 16; ++t) {
    const int cA = t & 1, cB = t % 3;
    bf16x8 xh[2], xl[2];
    bf16x8 qh[2][2], ql[2][2], kh[2][2], kl[2][2], vv[2][2];
#pragma unroll
    for (int ks = 0; ks < 2; ++ks) {
      const int kc = 2 * (ks * 4 + rsel);
      frag_split(&Af[cA][ra * 64], kc ^ ((ra & 7) << 1), xh[ks], xl[ks]);
#pragma unroll
      for (int n = 0; n < 2; ++n) {
        int rq = n * 16 + l15;
        frag_split(&Bf[cB][rq * 64], kc ^ ((rq & 7) << 1), qh[ks][n], ql[ks][n]);
        int rk = 32 + n * 16 + l15;
        frag_split(&Bf[cB][rk * 64], kc ^ ((rk & 7) << 1), kh[ks][n], kl[ks][n]);
        int rv = 64 + n * 16 + l15;
        vv[ks][n] = frag_cvt(&Bf[cB][rv * 64], kc ^ ((rv & 7) << 1));
      }
    }
    if (t < 15) STAGE_A((t + 1) & 1, t + 1);
    if (t < 14) STAGE_B((t + 2) % 3, t + 2);
#pragma unroll
    for (int ks = 0; ks < 2; ++ks)
#pragma unroll
      for (int n = 0; n < 2; ++n) {
        aq[n] = __builtin_amdgcn_mfma_f32_16x16x32_bf16(xh[ks], qh[ks][n], aq[n], 0, 0, 0);
        aq[n] = __builtin_amdgcn_mfma_f32_16x16x32_bf16(xh[ks], ql[ks][n], aq[n], 0, 0, 0);
        aq[n] = __builtin_amdgcn_mfma_f32_16x16x32_bf16(xl[ks], qh[ks][n], aq[n], 0, 0, 0);
        ak[n] = __builtin_amdgcn_mfma_f32_16x16x32_bf16(xh[ks], kh[ks][n], ak[n], 0, 0, 0);
        ak[n] = __builtin_amdgcn_mfma_f32_16x16x32_bf16(xh[ks], kl[ks][n], ak[n], 0, 0, 0);
        ak[n] = __builtin_amdgcn_mfma_f32_16x16x32_bf16(xl[ks], kh[ks][n], ak[n], 0, 0, 0);
        av[n] = __builtin_amdgcn_mfma_f32_16x16x32_bf16(xh[ks], vv[ks][n], av[n], 0, 0, 0);
      }
    if (t < 15) {
      if (t < 14) { asm volatile("s_waitcnt vmcnt(3) lgkmcnt(0)" ::: "memory"); }
      else        { asm volatile("s_waitcnt vmcnt(0) lgkmcnt(0)" ::: "memory"); }
      __builtin_amdgcn_sched_barrier(0);
      __builtin_amdgcn_s_barrier();
      __builtin_amdgcn_sched_barrier(0);
    }
  }
#undef STAGE_A
#undef STAGE_B

  // ---- epilogue: V store + BN-stat partials + raw dot partials ----
  float st[12];
#pragma unroll
  for (int j = 0; j < 12; ++j) st[j] = 0.f;
#pragma unroll
  for (int n = 0; n < 2; ++n)
#pragma unroll
    for (int r = 0; r < 4; ++r) {
      int row = w * 16 + rsel * 4 + r;
      int col = nt * 32 + n * 16 + l15;
      float vq = aq[n][r], vk = ak[n][r], vvv = av[n][r];
      V[row * 2048 + col] = vvv;
      int p = (r & 1) * 2;
      st[0 + p] += vq;  st[1 + p] += vq * vq;
      st[4 + p] += vk;  st[5 + p] += vk * vk;
      st[8 + p] += vvv; st[9 + p] += vvv * vvv;
    }
#pragma unroll
  for (int j = 0; j < 12; ++j) st[j] = wave_red(st[j]);
  if (lane == 0) {
#pragma unroll
    for (int j = 0; j < 12; ++j) red[w * 12 + j] = st[j];
  }

  // dots: per lane, 2 b's (its row-quad), products over its 2 cols
  float d8[2][8];
#pragma unroll
  for (int bb = 0; bb < 2; ++bb) {
    int rb = bb * 2;
    d8[bb][0] = aq[0][rb] * ak[0][rb]     + aq[1][rb] * ak[1][rb];
    d8[bb][1] = aq[0][rb] * ak[0][rb + 1] + aq[1][rb] * ak[1][rb + 1];
    d8[bb][2] = aq[0][rb + 1] * ak[0][rb]     + aq[1][rb + 1] * ak[1][rb];
    d8[bb][3] = aq[0][rb + 1] * ak[0][rb + 1] + aq[1][rb + 1] * ak[1][rb + 1];
    d8[bb][4] = aq[0][rb] + aq[1][rb];
    d8[bb][5] = aq[0][rb + 1] + aq[1][rb + 1];
    d8[bb][6] = ak[0][rb] + ak[1][rb];
    d8[bb][7] = ak[0][rb + 1] + ak[1][rb + 1];
  }
#pragma unroll
  for (int bb = 0; bb < 2; ++bb)
#pragma unroll
    for (int j = 0; j < 8; ++j) {
      float v = d8[bb][j];
      v += __shfl_xor(v, 1); v += __shfl_xor(v, 2);
      v += __shfl_xor(v, 4); v += __shfl_xor(v, 8);
      d8[bb][j] = v;
    }
  if (l15 == 0) {
#pragma unroll
    for (int bb = 0; bb < 2; ++bb) {
      int b = w * 8 + rsel * 2 + bb;
#pragma unroll
      for (int j = 0; j < 8; ++j) sdot[(nt * 64 + b) * 8 + j] = d8[bb][j];
    }
  }
  __syncthreads();
  if (tid < 12) {
    float s = 0.f;
    for (int i = 0; i < 8; ++i) s += red[i * 12 + tid];
    sq[tid * 64 + nt] = s;   // transposed [12][64]
  }
}

// ============== K2: fused attention + out GEMM ==============
// grid 64 (col-tiles of 16), 512 threads. A = attn built on the fly from V,
// B = Wo. Both 3-buf 2-ahead. Writes proj (+bias) and out BN-stat partials.
__global__ __launch_bounds__(512) void out_fused(const float* __restrict__ V,
                                                 const float* __restrict__ sq,
                                                 const float* __restrict__ sdot,
                                                 const float* __restrict__ Wo,
                                                 const float* __restrict__ bo,
                                                 const float* __restrict__ g_q, const float* __restrict__ b_q,
                                                 const float* __restrict__ g_k, const float* __restrict__ b_k,
                                                 const float* __restrict__ g_v, const float* __restrict__ b_v,
                                                 float* __restrict__ proj,
                                                 float* __restrict__ so) {
  __shared__ alignas(16) float Af[3][128 * 64];  // 96 KB (V tiles)
  __shared__ alignas(16) float Bf[3][16 * 64];   // 12 KB (Wo tiles)
  __shared__ float Fl[1024];                     // [b][h][8] reduced dots
  __shared__ float sstat[12];
  __shared__ float red[32];

  const int nt = blockIdx.x;
  const int tid = threadIdx.x, w = tid >> 6, lane = tid & 63;
  const int rsel = lane >> 4, ch = lane & 15, l15 = lane & 15;

#define STAGE_V(c, tt) do {                                                   \
    _Pragma("unroll")                                                         \
    for (int j = 0; j < 4; ++j) {                                             \
      int rl = w * 16 + j * 4 + rsel;                                         \
      GLDS16(V + rl * 2048 + (tt) * 64 + ((ch ^ ((rl & 7) << 1)) << 2),       \
             &Af[c][(w * 16 + j * 4) * 64]);                                  \
    }                                                                         \
  } while (0)

#define STAGE_W(c, tt) do {                                                   \
    if (w < 4) {                                                              \
      int rl = w * 4 + rsel;                                                  \
      GLDS16(Wo + (nt * 16 + rl) * 2048 + (tt) * 64 +                         \
                 ((ch ^ ((rl & 7) << 1)) << 2),                               \
             &Bf[c][(w * 4) * 64]);                                           \
    }                                                                         \
  } while (0)

  STAGE_V(0, 0); STAGE_W(0, 0);
  STAGE_V(1, 1); STAGE_W(1, 1);

  // prologue reductions (overlap with staging latency)
  {
    float s = sq[w * 64 + lane];
    s = wave_red(s);
    if (lane == 0) sstat[w] = s;
    if (w < 4) {
      float s2 = sq[(8 + w) * 64 + lane];
      s2 = wave_red(s2);
      if (lane == 0) sstat[8 + w] = s2;
    }
  }
#pragma unroll
  for (int e2 = 0; e2 < 2; ++e2) {
    int e = tid * 2 + e2;
    int b = e >> 4, hh = (e >> 3) & 1, j = e & 7;
    float f = 0.f;
    for (int i = 0; i < 32; ++i) f += sdot[((hh * 32 + i) * 64 + b) * 8 + j];
    Fl[e] = f;
  }
  __syncthreads();

  // per-lane attention coefficients (row = A-operand row of this lane)
  const int arow = w * 16 + l15, bidx = arow >> 1, nch = arow & 1;
  float ca0, cb0, cg0, ca1, cb1, cg1;
  {
    const float CNT = 131072.f, CNTD = 1024.f;
    float qm = sstat[0 + 2 * nch] / CNT, qv = sstat[1 + 2 * nch] / CNT - qm * qm;
    float qs = g_q[nch] * rsqrtf(qv + EPS), qo = b_q[nch] - qm * qs;
    float km0 = sstat[4] / CNT, kv0 = sstat[5] / CNT - km0 * km0;
    float ks0 = g_k[0] * rsqrtf(kv0 + EPS), ko0 = b_k[0] - km0 * ks0;
    float km1 = sstat[6] / CNT, kv1 = sstat[7] / CNT - km1 * km1;
    float ks1 = g_k[1] * rsqrtf(kv1 + EPS), ko1 = b_k[1] - km1 * ks1;
    float vm0 = sstat[8] / CNT, vv0 = sstat[9] / CNT - vm0 * vm0;
    float vs0 = g_v[0] * rsqrtf(vv0 + EPS), vo0 = b_v[0] - vm0 * vs0;
    float vm1 = sstat[10] / CNT, vv1 = sstat[11] / CNT - vm1 * vm1;
    float vs1 = g_v[1] * rsqrtf(vv1 + EPS), vo1 = b_v[1] - vm1 * vs1;
#pragma unroll
    for (int h = 0; h < 2; ++h) {
      const float* F = &Fl[bidx * 16 + h * 8];
      float p0 = qs * ks0 * F[nch * 2 + 0] + qs * ko0 * F[4 + nch] +
                 qo * ks0 * F[6] + qo * ko0 * CNTD;
      float p1 = qs * ks1 * F[nch * 2 + 1] + qs * ko1 * F[4 + nch] +
                 qo * ks1 * F[7] + qo * ko1 * CNTD;
      float di = 1.f / (p0 + p1);
      float a = di * p0 * vs0, bct = di * p1 * vs1;
      float g = di * (p0 * vo0 + p1 * vo1);
      if (h == 0) { ca0 = a; cb0 = bct; cg0 = g; }
      else        { ca1 = a; cb1 = bct; cg1 = g; }
    }
  }

  f32x4 acc = (f32x4){0.f, 0.f, 0.f, 0.f};
  const int re = arow & ~1, ro = re + 1;

#pragma unroll
  for (int t = 0; t < 32; ++t) {
    const int cc = t % 3;
    const float mal = (t < 16) ? ca0 : ca1;
    const float mbe = (t < 16) ? cb0 : cb1;
    const float mga = (t < 16) ? cg0 : cg1;
    bf16x8 fa[2], fb[2];
#pragma unroll
    for (int ks = 0; ks < 2; ++ks) {
      const int kc = 2 * (ks * 4 + rsel);
      const int pe = kc ^ ((re & 7) << 1), po = kc ^ ((ro & 7) << 1);
      const float* bev = &Af[cc][re * 64];
      const float* bov_ = &Af[cc][ro * 64];
      float4 e0 = *(const float4*)(bev + pe * 4);
      float4 e1 = *(const float4*)(bev + pe * 4 + 4);
      float4 o0 = *(const float4*)(bov_ + po * 4);
      float4 o1 = *(const float4*)(bov_ + po * 4 + 4);
      float ve[8] = {e0.x, e0.y, e0.z, e0.w, e1.x, e1.y, e1.z, e1.w};
      float vo[8] = {o0.x, o0.y, o0.z, o0.w, o1.x, o1.y, o1.z, o1.w};
      bf16x8 r;
#pragma unroll
      for (int i = 0; i < 8; ++i)
        r[i] = (__bf16)fmaf(mal, ve[i], fmaf(mbe, vo[i], mga));
      fa[ks] = r;
      fb[ks] = frag_cvt(&Bf[cc][l15 * 64], kc ^ ((l15 & 7) << 1));
    }
    if (t < 30) { STAGE_V((t + 2) % 3, t + 2); STAGE_W((t + 2) % 3, t + 2); }
    acc = __builtin_amdgcn_mfma_f32_16x16x32_bf16(fa[0], fb[0], acc, 0, 0, 0);
    acc = __builtin_amdgcn_mfma_f32_16x16x32_bf16(fa[1], fb[1], acc, 0, 0, 0);
    if (t < 31) {
      if (t < 30) {
        if (w < 4) { asm volatile("s_waitcnt vmcnt(5) lgkmcnt(0)" ::: "memory"); }
        else       { asm volatile("s_waitcnt vmcnt(4) lgkmcnt(0)" ::: "memory"); }
      } else       { asm volatile("s_waitcnt vmcnt(0) lgkmcnt(0)" ::: "memory"); }
      __builtin_amdgcn_sched_barrier(0);
      __builtin_amdgcn_s_barrier();
      __builtin_amdgcn_sched_barrier(0);
    }
  }
#undef STAGE_V
#undef STAGE_W

  // epilogue: proj = acc + bias; per-channel partial stats
  int col = nt * 16 + l15;
  float bov = bo[col];
  float s0 = 0, q0 = 0, s1 = 0, q1 = 0;
#pragma unroll
  for (int r = 0; r < 4; ++r) {
    int grow = w * 16 + rsel * 4 + r;
    float v = acc[r] + bov;
    proj[grow * 1024 + col] = v;
    if (r & 1) { s1 += v; q1 += v * v; } else { s0 += v; q0 += v * v; }
  }
  s0 = wave_red(s0); q0 = wave_red(q0); s1 = wave_red(s1); q1 = wave_red(q1);
  if (lane == 0) { red[w * 4 + 0] = s0; red[w * 4 + 1] = q0; red[w * 4 + 2] = s1; red[w * 4 + 3] = q1; }
  __syncthreads();
  if (tid == 0) {
    float a0 = 0, a1 = 0, a2 = 0, a3 = 0;
    for (int i = 0; i < 8; ++i) {
      a0 += red[i * 4 + 0]; a1 += red[i * 4 + 1];
      a2 += red[i * 4 + 2]; a3 += red[i * 4 + 3];
    }
    *(float4*)(so + nt * 4) = (float4){a0, a1, a2, a3};
  }
}

// ============== K3: reduce 64 stat partials + final BN normalize ==============
__global__ __launch_bounds__(256) void final_kernel(const float* __restrict__ proj,
                                                    const float* __restrict__ so,
                                                    const float* __restrict__ g_bn,
                                                    const float* __restrict__ b_bn,
                                                    float* __restrict__ out) {
  __shared__ float sm[4];
  int tid = threadIdx.x;
  int r = blockIdx.x;
  if (tid < 64) {
    float4 p = *(const float4*)(so + tid * 4);
    float a0 = wave_red(p.x), a1 = wave_red(p.y), a2 = wave_red(p.z), a3 = wave_red(p.w);
    if (tid == 0) { sm[0] = a0; sm[1] = a1; sm[2] = a2; sm[3] = a3; }
  }
  __syncthreads();
  int ch = r & 1;
  float m = (ch ? sm[2] : sm[0]) / 65536.f;
  float var = (ch ? sm[3] : sm[1]) / 65536.f - m * m;
  float sc = g_bn[ch] * rsqrtf(var + EPS);
  float sh = b_bn[ch] - m * sc;
  float4 v = *(const float4*)(proj + r * 1024 + tid * 4);
  float4 o = {v.x * sc + sh, v.y * sc + sh, v.z * sc + sh, v.w * sc + sh};
  *(float4*)(out + r * 1024 + tid * 4) = o;
}

extern "C" void kernel_launch(void* const* d_in, const int* in_sizes, int n_in,
                              void* d_out, int out_size, void* d_ws, size_t ws_size,
                              hipStream_t stream) {
  (void)in_sizes; (void)n_in; (void)out_size; (void)ws_size;
  const float* x    = (const float*)d_in[0];
  const float* Wq   = (const float*)d_in[1];
  const float* Wk   = (const float*)d_in[2];
  const float* Wv   = (const float*)d_in[3];
  const float* Wo   = (const float*)d_in[4];
  const float* bo   = (const float*)d_in[5];
  const float* g_q  = (const float*)d_in[6];
  const float* b_q  = (const float*)d_in[7];
  const float* g_k  = (const float*)d_in[8];
  const float* b_k  = (const float*)d_in[9];
  const float* g_v  = (const float*)d_in[10];
  const float* b_v  = (const float*)d_in[11];
  const float* g_bn = (const float*)d_in[12];
  const float* b_bn = (const float*)d_in[13];
  char* ws = (char*)d_ws;
  float* out = (float*)d_out;

  float* V    = (float*)(ws + OFF_V);
  float* sq   = (float*)(ws + OFF_SQ);
  float* sdot = (float*)(ws + OFF_SDOT);
  float* so   = (float*)(ws + OFF_SO);
  float* proj = (float*)(ws + OFF_PROJ);

  hipLaunchKernelGGL(qkv_gemm,     dim3(64),  dim3(512), 0, stream, x, Wq, Wk, Wv, V, sq, sdot);
  hipLaunchKernelGGL(out_fused,    dim3(64),  dim3(512), 0, stream, V, sq, sdot, Wo, bo,
                     g_q, b_q, g_k, b_k, g_v, b_v, proj, so);
  hipLaunchKernelGGL(final_kernel, dim3(128), dim3(256), 0, stream, proj, so, g_bn, b_bn, out);
}

// Round 8
// 40.906 us; speedup vs baseline: 2.1206x; 2.1206x over previous
//
#include <hip/hip_runtime.h>
#include <stdint.h>

typedef __bf16 bf16x8 __attribute__((ext_vector_type(8)));
typedef float f32x4 __attribute__((ext_vector_type(4)));

#define EPS 1e-5f

// ---- workspace layout (bytes) ----
#define OFF_SQ    0                       // 192*4 f32: per-block qkv BN partials
#define OFF_Q     4096                    // q,k,v f32 128x2048 each = 3 MB
#define OFF_AHI   (OFF_Q + 3145728)       // attn bf16 128x2048 = 512 KB
#define OFF_SO    (OFF_AHI + 524288)      // 128*4 f32: out BN partials
#define OFF_PROJ  (OFF_SO + 4096)         // 128x1024 f32 = 512 KB

static __device__ __forceinline__ unsigned short f2b(float f) {
  return __builtin_bit_cast(unsigned short, (__bf16)f);
}

__device__ __forceinline__ float wave_red(float v) {
#pragma unroll
  for (int o = 32; o > 0; o >>= 1) v += __shfl_down(v, o);
  return v;
}

#define GLDS16(g, l)                                             \
  __builtin_amdgcn_global_load_lds(                              \
      (const __attribute__((address_space(1))) void*)(g),        \
      (__attribute__((address_space(3))) void*)(l), 16, 0, 0)

// Read global f32 chunks c0 (even) and c0+1 from a swizzled LDS row.
// Position p holds global chunk p ^ s (s = row&7, flips low 3 bits -> banks
// spread across all 8 groups, conflict-free). Pair is at q0 and q0^1.
static __device__ __forceinline__ void frag_split(const float* base, int c0, int s,
                                                  bf16x8& hi, bf16x8& lo) {
  int q0 = c0 ^ s;
  float4 v0 = *(const float4*)(base + q0 * 4);
  float4 v1 = *(const float4*)(base + (q0 ^ 1) * 4);
  float a[8] = {v0.x, v0.y, v0.z, v0.w, v1.x, v1.y, v1.z, v1.w};
#pragma unroll
  for (int i = 0; i < 8; ++i) {
    __bf16 h = (__bf16)a[i];
    hi[i] = h;
    lo[i] = (__bf16)(a[i] - (float)h);
  }
}
static __device__ __forceinline__ bf16x8 frag_cvt(const float* base, int c0, int s) {
  int q0 = c0 ^ s;
  float4 v0 = *(const float4*)(base + q0 * 4);
  float4 v1 = *(const float4*)(base + (q0 ^ 1) * 4);
  bf16x8 r;
  r[0] = (__bf16)v0.x; r[1] = (__bf16)v0.y; r[2] = (__bf16)v0.z; r[3] = (__bf16)v0.w;
  r[4] = (__bf16)v1.x; r[5] = (__bf16)v1.y; r[6] = (__bf16)v1.z; r[7] = (__bf16)v1.w;
  return r;
}

// K1: fused Q/K/V GEMM, split-precision (hh+hl+lh). A = x f32 staged via glds,
// B = W f32 staged via glds; hi/lo conversion at fragment read. 3-buffer
// rotation, stage 2 tiles ahead into the buffer freed at the last barrier.
// BM=128, BN=32, BK=64, K=1024 (16 iters). grid = 3 mats x 64 nt = 192.
__global__ __launch_bounds__(256) void qkv_gemm(const float* __restrict__ x,
                                                const float* __restrict__ Wq,
                                                const float* __restrict__ Wk,
                                                const float* __restrict__ Wv,
                                                float* __restrict__ qkv,
                                                float* __restrict__ sq) {
  __shared__ alignas(16) float Af[3][128 * 64];   // 96 KB
  __shared__ alignas(16) float Bf[3][32 * 64];    // 24 KB
  __shared__ float red[16];

  int mat = blockIdx.x >> 6;
  int nt  = blockIdx.x & 63;
  const float* W = (mat == 0) ? Wq : ((mat == 1) ? Wk : Wv);
  float* outp = qkv + mat * 262144;

  int tid = threadIdx.x, w = tid >> 6, lane = tid & 63;
  int rsel = lane >> 4, ch = lane & 15, l15 = lane & 15;

#define STAGE_Q(c, tt) do {                                                   \
    _Pragma("unroll")                                                         \
    for (int j = 0; j < 8; ++j) {                                             \
      int rl = w * 32 + j * 4 + rsel;                                         \
      GLDS16(x + rl * 1024 + (tt) * 64 + ((ch ^ (rl & 7)) << 2),              \
             &Af[c][(w * 32 + j * 4) * 64]);                                  \
    }                                                                         \
    _Pragma("unroll")                                                         \
    for (int j = 0; j < 2; ++j) {                                             \
      int rl = w * 8 + j * 4 + rsel;                                          \
      GLDS16(W + (nt * 32 + rl) * 1024 + (tt) * 64 +                          \
                 ((ch ^ (rl & 7)) << 2),                                      \
             &Bf[c][(w * 8 + j * 4) * 64]);                                   \
    }                                                                         \
  } while (0)

  f32x4 acc[2][2];
#pragma unroll
  for (int m = 0; m < 2; ++m)
#pragma unroll
    for (int n = 0; n < 2; ++n) acc[m][n] = (f32x4){0.f, 0.f, 0.f, 0.f};

  // prologue: tiles 0,1 -> bufs 0,1
  STAGE_Q(0, 0);
  STAGE_Q(1, 1);
  __syncthreads();

#pragma unroll
  for (int t = 0; t < 16; ++t) {
    const int c = t % 3;
    bf16x8 fah[2][2], fal[2][2], fbh[2][2], fbl[2][2];
#pragma unroll
    for (int ks = 0; ks < 2; ++ks) {
      int kc = ks * 4 + rsel;
#pragma unroll
      for (int m = 0; m < 2; ++m) {
        int ra = w * 32 + m * 16 + l15;
        frag_split(&Af[c][ra * 64], kc * 2, ra & 7, fah[ks][m], fal[ks][m]);
      }
#pragma unroll
      for (int n = 0; n < 2; ++n) {
        int rb = n * 16 + l15;
        frag_split(&Bf[c][rb * 64], kc * 2, rb & 7, fbh[ks][n], fbl[ks][n]);
      }
    }
    if (t < 14) { STAGE_Q((t + 2) % 3, t + 2); }   // into freed buffer
#pragma unroll
    for (int ks = 0; ks < 2; ++ks)
#pragma unroll
      for (int m = 0; m < 2; ++m)
#pragma unroll
        for (int n = 0; n < 2; ++n) {
          acc[m][n] = __builtin_amdgcn_mfma_f32_16x16x32_bf16(fah[ks][m], fbh[ks][n], acc[m][n], 0, 0, 0);
          acc[m][n] = __builtin_amdgcn_mfma_f32_16x16x32_bf16(fah[ks][m], fbl[ks][n], acc[m][n], 0, 0, 0);
          acc[m][n] = __builtin_amdgcn_mfma_f32_16x16x32_bf16(fal[ks][m], fbh[ks][n], acc[m][n], 0, 0, 0);
        }
    if (t < 15) {
      if (t < 14) { asm volatile("s_waitcnt vmcnt(10) lgkmcnt(0)" ::: "memory"); }
      else        { asm volatile("s_waitcnt vmcnt(0) lgkmcnt(0)" ::: "memory"); }
      __builtin_amdgcn_sched_barrier(0);
      __builtin_amdgcn_s_barrier();
      __builtin_amdgcn_sched_barrier(0);
    }
  }
#undef STAGE_Q

  // epilogue: store f32 + per-channel (row parity) partial stats, deterministic
  float s0 = 0, q0 = 0, s1 = 0, q1 = 0;
#pragma unroll
  for (int m = 0; m < 2; ++m)
#pragma unroll
    for (int n = 0; n < 2; ++n)
#pragma unroll
      for (int r = 0; r < 4; ++r) {
        int row = w * 32 + m * 16 + (lane >> 4) * 4 + r;
        int col = nt * 32 + n * 16 + l15;
        float v = acc[m][n][r];
        outp[row * 2048 + col] = v;
        if (r & 1) { s1 += v; q1 += v * v; } else { s0 += v; q0 += v * v; }
      }
  s0 = wave_red(s0); q0 = wave_red(q0); s1 = wave_red(s1); q1 = wave_red(q1);
  if (lane == 0) { red[w * 4 + 0] = s0; red[w * 4 + 1] = q0; red[w * 4 + 2] = s1; red[w * 4 + 3] = q1; }
  __syncthreads();
  if (tid == 0) {
    float a0 = 0, a1 = 0, a2 = 0, a3 = 0;
    for (int i = 0; i < 4; ++i) { a0 += red[i * 4 + 0]; a1 += red[i * 4 + 1]; a2 += red[i * 4 + 2]; a3 += red[i * 4 + 3]; }
    *(float4*)(sq + blockIdx.x * 4) = (float4){a0, a1, a2, a3};
  }
}

// K2: per-(b,h) linear attention; reduces qkv stat partials in-kernel;
// writes attn as single bf16.
__global__ __launch_bounds__(256) void attn_kernel(const float* __restrict__ qkv,
                                                   const float* __restrict__ sq,
                                                   ushort* __restrict__ ahi,
                                                   const float* __restrict__ g_q, const float* __restrict__ b_q,
                                                   const float* __restrict__ g_k, const float* __restrict__ b_k,
                                                   const float* __restrict__ g_v, const float* __restrict__ b_v) {
  __shared__ float sm[12];
  __shared__ float red[16];
  __shared__ float bc[4];
  int bh = blockIdx.x, b = bh >> 1, h = bh & 1;
  int tid = threadIdx.x, w = tid >> 6, lane = tid & 63;

  // reduce 192 per-block partials: wave w (w<3) handles mat w (64 entries)
  if (tid < 192) {
    float4 p = *(const float4*)(sq + tid * 4);
    float a0 = wave_red(p.x), a1 = wave_red(p.y), a2 = wave_red(p.z), a3 = wave_red(p.w);
    if (lane == 0) { sm[w * 4 + 0] = a0; sm[w * 4 + 1] = a1; sm[w * 4 + 2] = a2; sm[w * 4 + 3] = a3; }
  }
  __syncthreads();

  const float cnt = 131072.f;
  float qs[2], qo[2], kc_[2], ko[2], vs[2], vo[2];
#pragma unroll
  for (int c = 0; c < 2; ++c) {
    float m, var, inv;
    m = sm[0 + 2 * c] / cnt; var = sm[1 + 2 * c] / cnt - m * m; inv = rsqrtf(var + EPS);
    qs[c] = g_q[c] * inv; qo[c] = b_q[c] - m * qs[c];
    m = sm[4 + 2 * c] / cnt; var = sm[5 + 2 * c] / cnt - m * m; inv = rsqrtf(var + EPS);
    kc_[c] = g_k[c] * inv; ko[c] = b_k[c] - m * kc_[c];
    m = sm[8 + 2 * c] / cnt; var = sm[9 + 2 * c] / cnt - m * m; inv = rsqrtf(var + EPS);
    vs[c] = g_v[c] * inv; vo[c] = b_v[c] - m * vs[c];
  }

  const float* Q = qkv;
  const float* K = qkv + 262144;
  const float* V = qkv + 524288;
  const float* q0p = Q + (b * 2 + 0) * 2048 + h * 1024;
  const float* q1p = Q + (b * 2 + 1) * 2048 + h * 1024;
  const float* k0p = K + (b * 2 + 0) * 2048 + h * 1024;
  const float* k1p = K + (b * 2 + 1) * 2048 + h * 1024;
  const float* v0p = V + (b * 2 + 0) * 2048 + h * 1024;
  const float* v1p = V + (b * 2 + 1) * 2048 + h * 1024;

  float p00 = 0, p01 = 0, p10 = 0, p11 = 0;
#pragma unroll
  for (int i = 0; i < 4; ++i) {
    int d = tid + i * 256;
    float a0 = q0p[d] * qs[0] + qo[0];
    float a1 = q1p[d] * qs[1] + qo[1];
    float c0 = k0p[d] * kc_[0] + ko[0];
    float c1 = k1p[d] * kc_[1] + ko[1];
    p00 += a0 * c0; p01 += a0 * c1; p10 += a1 * c0; p11 += a1 * c1;
  }
  p00 = wave_red(p00); p01 = wave_red(p01); p10 = wave_red(p10); p11 = wave_red(p11);
  if (lane == 0) { red[w * 4 + 0] = p00; red[w * 4 + 1] = p01; red[w * 4 + 2] = p10; red[w * 4 + 3] = p11; }
  __syncthreads();
  if (tid < 4) bc[tid] = red[0 + tid] + red[4 + tid] + red[8 + tid] + red[12 + tid];
  __syncthreads();
  float s00 = bc[0], s01 = bc[1], s10 = bc[2], s11 = bc[3];
  float di0 = 1.f / (s00 + s01), di1 = 1.f / (s10 + s11);
  int o0 = (b * 2 + 0) * 2048 + h * 1024;
  int o1 = (b * 2 + 1) * 2048 + h * 1024;
#pragma unroll
  for (int i = 0; i < 4; ++i) {
    int d = tid + i * 256;
    float v0 = v0p[d] * vs[0] + vo[0];
    float v1 = v1p[d] * vs[1] + vo[1];
    ahi[o0 + d] = f2b((s00 * v0 + s01 * v1) * di0);
    ahi[o1 + d] = f2b((s10 * v0 + s11 * v1) * di1);
  }
}

// K3: out GEMM full-K (128x2048 @ Wo^T -> 128x1024), plain bf16.
// A = attn bf16 via glds; B = Wo f32 via glds, cvt on read.
// BM=64, BN=16, BK=128, K=2048 (16 iters). grid = 2 mt x 64 nt = 128.
__global__ __launch_bounds__(256) void out_gemm(const ushort* __restrict__ ahi,
                                                const float* __restrict__ Wo,
                                                const float* __restrict__ bo,
                                                float* __restrict__ proj,
                                                float* __restrict__ so) {
  __shared__ alignas(16) ushort Ab[3][64 * 128];   // 48 KB
  __shared__ alignas(16) float  Bf[3][16 * 128];   // 24 KB
  __shared__ float red[16];

  int mt = blockIdx.x >> 6;
  int nt = blockIdx.x & 63;

  int tid = threadIdx.x, w = tid >> 6, lane = tid & 63;
  int rsel4 = lane >> 4, ch16 = lane & 15;
  int rsel2 = lane >> 5, ch32 = lane & 31;

#define STAGE_O(c, tt) do {                                                   \
    _Pragma("unroll")                                                         \
    for (int j = 0; j < 4; ++j) {                                             \
      int rl = w * 16 + j * 4 + rsel4;                                        \
      GLDS16(ahi + (mt * 64 + rl) * 2048 + (tt) * 128 +                       \
                 ((ch16 ^ (rl & 7)) << 3),                                    \
             &Ab[c][(w * 16 + j * 4) * 128]);                                 \
    }                                                                         \
    _Pragma("unroll")                                                         \
    for (int j = 0; j < 2; ++j) {                                             \
      int rl = w * 4 + j * 2 + rsel2;                                         \
      GLDS16(Wo + (nt * 16 + rl) * 2048 + (tt) * 128 +                        \
                 ((ch32 ^ (rl & 7)) << 2),                                    \
             &Bf[c][(w * 4 + j * 2) * 128]);                                  \
    }                                                                         \
  } while (0)

  f32x4 acc = (f32x4){0.f, 0.f, 0.f, 0.f};

  STAGE_O(0, 0);
  STAGE_O(1, 1);
  __syncthreads();

#pragma unroll
  for (int t = 0; t < 16; ++t) {
    const int c = t % 3;
    bf16x8 fa[4], fb[4];
#pragma unroll
    for (int ks = 0; ks < 4; ++ks) {
      int kc = ks * 4 + rsel4;
      int ra = w * 16 + (lane & 15);
      fa[ks] = *(const bf16x8*)(&Ab[c][ra * 128 + ((kc ^ (ra & 7)) << 3)]);
      int rb = lane & 15;
      fb[ks] = frag_cvt(&Bf[c][rb * 128], kc * 2, rb & 7);
    }
    if (t < 14) { STAGE_O((t + 2) % 3, t + 2); }
#pragma unroll
    for (int ks = 0; ks < 4; ++ks)
      acc = __builtin_amdgcn_mfma_f32_16x16x32_bf16(fa[ks], fb[ks], acc, 0, 0, 0);
    if (t < 15) {
      if (t < 14) { asm volatile("s_waitcnt vmcnt(6) lgkmcnt(0)" ::: "memory"); }
      else        { asm volatile("s_waitcnt vmcnt(0) lgkmcnt(0)" ::: "memory"); }
      __builtin_amdgcn_sched_barrier(0);
      __builtin_amdgcn_s_barrier();
      __builtin_amdgcn_sched_barrier(0);
    }
  }
#undef STAGE_O

  // epilogue: proj = acc + bias; per-channel partial stats (deterministic)
  int col = nt * 16 + (lane & 15);
  float bov = bo[col];
  float s0 = 0, q0 = 0, s1 = 0, q1 = 0;
#pragma unroll
  for (int r = 0; r < 4; ++r) {
    int grow = mt * 64 + w * 16 + (lane >> 4) * 4 + r;
    float v = acc[r] + bov;
    proj[grow * 1024 + col] = v;
    if (r & 1) { s1 += v; q1 += v * v; } else { s0 += v; q0 += v * v; }
  }
  s0 = wave_red(s0); q0 = wave_red(q0); s1 = wave_red(s1); q1 = wave_red(q1);
  if (lane == 0) { red[w * 4 + 0] = s0; red[w * 4 + 1] = q0; red[w * 4 + 2] = s1; red[w * 4 + 3] = q1; }
  __syncthreads();
  if (tid == 0) {
    float a0 = 0, a1 = 0, a2 = 0, a3 = 0;
    for (int i = 0; i < 4; ++i) { a0 += red[i * 4 + 0]; a1 += red[i * 4 + 1]; a2 += red[i * 4 + 2]; a3 += red[i * 4 + 3]; }
    *(float4*)(so + blockIdx.x * 4) = (float4){a0, a1, a2, a3};
  }
}

// K4: reduce 128 stat partials + final BN normalize.
__global__ __launch_bounds__(256) void final_kernel(const float* __restrict__ proj,
                                                    const float* __restrict__ so,
                                                    const float* __restrict__ g_bn,
                                                    const float* __restrict__ b_bn,
                                                    float* __restrict__ out) {
  __shared__ float sm[8];
  int tid = threadIdx.x, w = tid >> 6;
  int r = blockIdx.x;
  if (tid < 128) {
    float4 p = *(const float4*)(so + tid * 4);
    float a0 = wave_red(p.x), a1 = wave_red(p.y), a2 = wave_red(p.z), a3 = wave_red(p.w);
    if ((tid & 63) == 0) { sm[w * 4 + 0] = a0; sm[w * 4 + 1] = a1; sm[w * 4 + 2] = a2; sm[w * 4 + 3] = a3; }
  }
  __syncthreads();
  float s0 = sm[0] + sm[4], q0 = sm[1] + sm[5];
  float s1 = sm[2] + sm[6], q1 = sm[3] + sm[7];
  int ch = r & 1;
  float m = (ch ? s1 : s0) / 65536.f;
  float var = (ch ? q1 : q0) / 65536.f - m * m;
  float sc = g_bn[ch] * rsqrtf(var + EPS);
  float sh = b_bn[ch] - m * sc;
  float4 v = *(const float4*)(proj + r * 1024 + tid * 4);
  float4 o = {v.x * sc + sh, v.y * sc + sh, v.z * sc + sh, v.w * sc + sh};
  *(float4*)(out + r * 1024 + tid * 4) = o;
}

extern "C" void kernel_launch(void* const* d_in, const int* in_sizes, int n_in,
                              void* d_out, int out_size, void* d_ws, size_t ws_size,
                              hipStream_t stream) {
  (void)in_sizes; (void)n_in; (void)out_size; (void)ws_size;
  const float* x    = (const float*)d_in[0];
  const float* Wq   = (const float*)d_in[1];
  const float* Wk   = (const float*)d_in[2];
  const float* Wv   = (const float*)d_in[3];
  const float* Wo   = (const float*)d_in[4];
  const float* bo   = (const float*)d_in[5];
  const float* g_q  = (const float*)d_in[6];
  const float* b_q  = (const float*)d_in[7];
  const float* g_k  = (const float*)d_in[8];
  const float* b_k  = (const float*)d_in[9];
  const float* g_v  = (const float*)d_in[10];
  const float* b_v  = (const float*)d_in[11];
  const float* g_bn = (const float*)d_in[12];
  const float* b_bn = (const float*)d_in[13];
  char* ws = (char*)d_ws;
  float* out = (float*)d_out;

  float*  sq   = (float*)(ws + OFF_SQ);
  float*  qkv  = (float*)(ws + OFF_Q);
  ushort* ahi  = (ushort*)(ws + OFF_AHI);
  float*  so   = (float*)(ws + OFF_SO);
  float*  proj = (float*)(ws + OFF_PROJ);

  hipLaunchKernelGGL(qkv_gemm,     dim3(192), dim3(256), 0, stream, x, Wq, Wk, Wv, qkv, sq);
  hipLaunchKernelGGL(attn_kernel,  dim3(128), dim3(256), 0, stream, qkv, sq, ahi,
                     g_q, b_q, g_k, b_k, g_v, b_v);
  hipLaunchKernelGGL(out_gemm,     dim3(128), dim3(256), 0, stream, ahi, Wo, bo, proj, so);
  hipLaunchKernelGGL(final_kernel, dim3(128), dim3(256), 0, stream, proj, so, g_bn, b_bn, out);
}